// Round 7
// baseline (3825.697 us; speedup 1.0000x reference)
//
#include <hip/hip_runtime.h>
#include <hip/hip_bf16.h>
#include <stdint.h>

#define BATCH 64
#define SEQ   512
#define HID   1024
#define VOC   4096
#define LROWS (SEQ*BATCH)   // 32768 output rows
#define HN    (BATCH*HID)   // 65536 elems per H state
#define NWG   64
#define NGRP  8             // barrier tree: 8 groups x 8 wgs
#define GSZ   8

typedef __attribute__((ext_vector_type(4))) float f32x4;
typedef __attribute__((ext_vector_type(8))) short short8;

__device__ __forceinline__ unsigned short f2bf(float f) {
    unsigned int u = __builtin_bit_cast(unsigned int, f);
    u += 0x7fffu + ((u >> 16) & 1u);   // round-to-nearest-even
    return (unsigned short)(u >> 16);
}

__device__ __forceinline__ float tanh_fast(float x) {
    // |z| stays O(1) here; e^{2x} cannot overflow. rel err ~1e-6.
    float e = __expf(2.f * x);
    return (e - 1.f) * __frcp_rn(e + 1.f);
}

// Write-through-to-LLC bf16 store: visible device-wide once vmcnt retires.
__device__ __forceinline__ void store_bf16_llc(unsigned short* p, unsigned short v) {
    unsigned int vv = v;
    asm volatile("global_store_short %0, %1, off sc0 sc1" :: "v"(p), "v"(vv) : "memory");
}

// async global->LDS, 16B per lane
#define GLL16(g, l) __builtin_amdgcn_global_load_lds( \
    (const __attribute__((address_space(1))) void*)(g), \
    (__attribute__((address_space(3))) void*)(l), 16, 0, 0)

// ---------------------------------------------------------------------------
// Tree barrier, all-relaxed, monotonic, at LLC. Layout (128B-spaced lines):
//   bar[grp*32]      : lcnt[grp]  (8 group arrival counters, 8-way contention)
//   bar[8*32]        : gcnt       (group-rep counter, 8-way contention)
//   bar[(16+grp)*32] : relay[grp] (per-group release line)
// Correctness does NOT depend on wg->XCD placement: all counters are
// agent-scope (LLC) atomics; groups are static wgid>>3. Hst data is made
// visible by sc0sc1 write-through stores + the vmcnt(0) drain before arrival
// (write-once-read-once ring => no stale-L2 hazard; round-4 audit applies).
// Deadlock safety: launched via hipLaunchCooperativeKernel => all 64 wgs
// guaranteed co-resident before any runs.
// ---------------------------------------------------------------------------
__device__ __forceinline__ void gbar_tree(unsigned* bar, unsigned gen, int grp) {
    asm volatile("s_waitcnt vmcnt(0)" ::: "memory");  // drain sc-stores
    __syncthreads();
    if (threadIdx.x == 0) {
        unsigned* lcnt  = bar + grp*32;
        unsigned* gcnt  = bar + 8*32;
        unsigned* relay = bar + (16 + grp)*32;
        unsigned a = __hip_atomic_fetch_add(lcnt, 1u, __ATOMIC_RELAXED,
                                            __HIP_MEMORY_SCOPE_AGENT);
        if (a + 1u == gen * GSZ) {            // group-last arrival (exactly one)
            unsigned go = __hip_atomic_fetch_add(gcnt, 1u, __ATOMIC_RELAXED,
                                                 __HIP_MEMORY_SCOPE_AGENT);
            if (go + 1u < gen * NGRP) {       // not globally last: wait for rest
                unsigned c;
                do {
                    __builtin_amdgcn_s_sleep(1);
                    c = __hip_atomic_load(gcnt, __ATOMIC_RELAXED,
                                          __HIP_MEMORY_SCOPE_AGENT);
                } while (c < gen * NGRP);
            }
            __hip_atomic_store(relay, gen, __ATOMIC_RELAXED,
                               __HIP_MEMORY_SCOPE_AGENT);
        } else {
            unsigned r;
            do {
                __builtin_amdgcn_s_sleep(1);
                r = __hip_atomic_load(relay, __ATOMIC_RELAXED,
                                      __HIP_MEMORY_SCOPE_AGENT);
            } while (r < gen);
        }
    }
    __syncthreads();
    asm volatile("" ::: "memory");   // no load hoisting above the spin
}

// ---------------------------------------------------------------------------
// Generic: in[R][C] f32  ->  out[C][R] bf16   (transpose + convert)
// ---------------------------------------------------------------------------
__global__ __launch_bounds__(256) void k_transpose_f32_bf16(
    const float* __restrict__ in, unsigned short* __restrict__ out, int R, int C)
{
    __shared__ float tile[64][65];
    const int tid = threadIdx.x;
    const int c0 = blockIdx.x * 64;
    const int r0 = blockIdx.y * 64;
    #pragma unroll
    for (int i = 0; i < 16; ++i) {
        int idx = tid + i*256;
        int r = idx >> 6, c = idx & 63;
        tile[r][c] = in[(size_t)(r0 + r)*C + c0 + c];
    }
    __syncthreads();
    #pragma unroll
    for (int i = 0; i < 16; ++i) {
        int idx = tid + i*256;
        int r = idx >> 6, c = idx & 63;
        out[(size_t)(c0 + r)*R + r0 + c] = f2bf(tile[c][r]);
    }
}

// ---------------------------------------------------------------------------
// Persistent cooperative recurrence. 64 wgs x 256 thr (4 waves).
// wg g owns output cols [16g,16g+16); W_hh^T slice in LDS (round-4 proven).
// Tree barrier per step (round-6 lever, now on the proven coop launch).
// ---------------------------------------------------------------------------
__global__ __launch_bounds__(256, 1) void k_rnn_persist(
    const unsigned short* __restrict__ WhhT, // [1024 c][1024 k] bf16
    const float* __restrict__ bh,            // [1024]
    const float* __restrict__ Wxh,           // [4096][1024] f32
    const int*   __restrict__ X,             // [64][512]
    const float* __restrict__ H0,            // [64][1024] f32
    unsigned short* __restrict__ Hst,        // [513][64][1024] bf16
    float* __restrict__ Hfin,                // [64][1024] f32 (out tail)
    unsigned* __restrict__ bar)              // barrier lines (zeroed per call)
{
    __shared__ unsigned short Wl[16*1024];   // [c][k], XOR-swizzled
    const int tid  = threadIdx.x;
    const int lane = tid & 63;
    const int wave = tid >> 6;               // row-tile 16*wave
    const int g    = blockIdx.x;             // col slice
    const int grp  = g >> 3;                 // barrier group

    // ---- stage W slice into LDS (once), swizzled: byte ^= (c&7)<<4 ----
    #pragma unroll
    for (int it = 0; it < 8; ++it) {
        int slot = it*256 + tid;             // 0..2047 (16B chunks)
        int c  = slot >> 7;                  // 0..15
        int k0 = (slot & 127) * 8;
        short8 v = *(const short8*)&WhhT[(size_t)(g*16 + c)*HID + k0];
        int byte = c*2048 + k0*2;
        byte ^= (c & 7) << 4;
        *(short8*)((char*)Wl + byte) = v;
    }
    // ---- init state slot 0 = bf16(H0): wg g writes batch row g (LLC-visible)
    for (int i = tid; i < 1024; i += 256) {
        int idx = g*1024 + i;
        store_bf16_llc(&Hst[idx], f2bf(H0[idx]));
    }

    const int col   = g*16 + (lane & 15);
    const float bhc = bh[col];
    const int rowbase = wave*16 + ((lane >> 4) * 4);

    // prefetch x-gather for t=0 (read-only data, safe before barrier)
    float xv[4];
    #pragma unroll
    for (int q = 0; q < 4; ++q) {
        int xi = X[(rowbase + q)*SEQ + 0];
        xv[q] = Wxh[(size_t)xi*HID + col];
    }

    unsigned gen = 1;
    gbar_tree(bar, gen, grp); gen++;   // slot 0 visible everywhere

    for (int t = 0; t < SEQ; ++t) {
        const unsigned short* Hin = Hst + (size_t)t * HN;
        // A fragments: rows 16w+(lane&15), k = ks*32 + (lane>>4)*8
        const unsigned short* arow =
            Hin + (size_t)(wave*16 + (lane & 15))*HID + (lane >> 4)*8;
        short8 af[32];
        #pragma unroll
        for (int ks = 0; ks < 32; ++ks)
            af[ks] = *(const short8*)(arow + ks*32);

        // prefetch next step's x-gather (H-independent; hides under MFMA)
        float xvn[4] = {0.f, 0.f, 0.f, 0.f};
        if (t + 1 < SEQ) {
            #pragma unroll
            for (int q = 0; q < 4; ++q) {
                int xi = X[(rowbase + q)*SEQ + (t + 1)];
                xvn[q] = Wxh[(size_t)xi*HID + col];
            }
        }

        f32x4 acc = (f32x4){0.f, 0.f, 0.f, 0.f};
        #pragma unroll
        for (int ks = 0; ks < 32; ++ks) {
            int byte = (lane & 15)*2048 + ks*64 + (lane >> 4)*16;
            byte ^= (lane & 7) << 4;
            short8 bf = *(const short8*)((char*)Wl + byte);
            acc = __builtin_amdgcn_mfma_f32_16x16x32_bf16(af[ks], bf, acc, 0, 0, 0);
        }

        unsigned short* Hout = Hst + (size_t)(t + 1) * HN;
        #pragma unroll
        for (int q = 0; q < 4; ++q) {
            float h = tanh_fast(acc[q] + xv[q] + bhc);
            store_bf16_llc(&Hout[(size_t)(rowbase + q)*HID + col], f2bf(h));
            if (t == SEQ - 1) Hfin[(rowbase + q)*HID + col] = h;
        }
        #pragma unroll
        for (int q = 0; q < 4; ++q) xv[q] = xvn[q];

        if (t + 1 < SEQ) { gbar_tree(bar, gen, grp); gen++; }  // none after last
    }
}

// ---------------------------------------------------------------------------
// Logits GEMM: C[L][4096] = A[L][1024](bf16) * Bt[4096][1024]^T(bf16) + b_q
// 128x128 tile, BK=64, 4 waves (2x2); XCD-aware block swizzle (8192 % 8 == 0)
// ---------------------------------------------------------------------------
__global__ __launch_bounds__(256) void k_gemm_logits(
    const unsigned short* __restrict__ A,   // [LROWS][1024] bf16
    const unsigned short* __restrict__ Bt,  // [4096][1024] bf16
    const float* __restrict__ bq,           // [4096]
    float* __restrict__ C)                  // [LROWS][4096]
{
    __shared__ unsigned short lA[128*64];   // row stride 64 bf16 (128B)
    __shared__ unsigned short lB[128*64];
    const int tid  = threadIdx.x;
    const int lane = tid & 63;
    const int wave = tid >> 6;
    const int wm = wave >> 1, wn = wave & 1;

    const int NBM = LROWS/128, NBN = VOC/128;          // 256 x 32 = 8192
    int lid = blockIdx.y * NBM + blockIdx.x;
    int swz = (lid & 7) * (NBM*NBN/8) + (lid >> 3);
    const int bm = swz % NBM;
    const int bn = swz / NBM;
    const int rowA0 = bm * 128;
    const int rowB0 = bn * 128;

    f32x4 acc[4][4];
    #pragma unroll
    for (int i = 0; i < 4; ++i)
        #pragma unroll
        for (int j = 0; j < 4; ++j)
            acc[i][j] = (f32x4){0.f, 0.f, 0.f, 0.f};

    for (int kt = 0; kt < HID; kt += 64) {
        __syncthreads();
        #pragma unroll
        for (int i = 0; i < 4; ++i) {
            int slot = i*256 + tid;          // 16B slots, 8 per tile row
            int row  = slot >> 3;
            int colb = (slot & 7) * 8;       // bf16 col
            const unsigned short* ga = A  + (size_t)(rowA0 + row)*HID + kt + colb;
            const unsigned short* gb = Bt + (size_t)(rowB0 + row)*HID + kt + colb;
            unsigned short* la = lA + (i*256 + (tid >> 6)*64)*8;  // wave-uniform
            unsigned short* lb = lB + (i*256 + (tid >> 6)*64)*8;
            GLL16(ga, la);
            GLL16(gb, lb);
        }
        __syncthreads();
        #pragma unroll
        for (int ks = 0; ks < 2; ++ks) {
            short8 af[4], bf[4];
            #pragma unroll
            for (int i = 0; i < 4; ++i) {
                int row = wm*64 + i*16 + (lane & 15);
                int k   = ks*32 + (lane >> 4)*8;
                af[i] = *(const short8*)&lA[row*64 + k];
            }
            #pragma unroll
            for (int j = 0; j < 4; ++j) {
                int row = wn*64 + j*16 + (lane & 15);
                int k   = ks*32 + (lane >> 4)*8;
                bf[j] = *(const short8*)&lB[row*64 + k];
            }
            #pragma unroll
            for (int i = 0; i < 4; ++i)
                #pragma unroll
                for (int j = 0; j < 4; ++j)
                    acc[i][j] = __builtin_amdgcn_mfma_f32_16x16x32_bf16(af[i], bf[j], acc[i][j], 0, 0, 0);
        }
    }

    #pragma unroll
    for (int i = 0; i < 4; ++i) {
        int rbase = rowA0 + wm*64 + i*16 + (lane >> 4)*4;
        #pragma unroll
        for (int j = 0; j < 4; ++j) {
            int c = rowB0 + wn*64 + j*16 + (lane & 15);
            float bqv = bq[c];
            #pragma unroll
            for (int reg = 0; reg < 4; ++reg)
                C[(size_t)(rbase + reg)*VOC + c] = acc[i][j][reg] + bqv;
        }
    }
}

// ---------------------------------------------------------------------------
extern "C" void kernel_launch(void* const* d_in, const int* in_sizes, int n_in,
                              void* d_out, int out_size, void* d_ws, size_t ws_size,
                              hipStream_t stream) {
    const int*   X   = (const int*)d_in[0];
    const float* H0  = (const float*)d_in[1];
    const float* Wxh = (const float*)d_in[2];
    const float* Whh = (const float*)d_in[3];
    const float* bh  = (const float*)d_in[4];
    const float* Whq = (const float*)d_in[5];
    const float* bq  = (const float*)d_in[6];
    float* out = (float*)d_out;

    // workspace layout
    char* ws = (char*)d_ws;
    unsigned* bar = (unsigned*)ws;                                        // 4 KB
    unsigned short* WhhT = (unsigned short*)(ws + 4096);                  // 2 MB
    unsigned short* BtHq = (unsigned short*)(ws + 4096 + (size_t)2*1024*1024);   // 8 MB
    unsigned short* Hst  = (unsigned short*)(ws + 4096 + (size_t)10*1024*1024);  // 513 slots bf16

    hipMemsetAsync(bar, 0, 4096, stream);   // barrier counters start at 0 every call

    k_transpose_f32_bf16<<<dim3(HID/64, HID/64), 256, 0, stream>>>(Whh, WhhT, HID, HID);
    k_transpose_f32_bf16<<<dim3(VOC/64, HID/64), 256, 0, stream>>>(Whq, BtHq, HID, VOC);

    float* Hfin = out + (size_t)LROWS * VOC;
    // Cooperative launch (proven rounds 2-4 at this resource profile):
    // guarantees all 64 wgs co-resident => spin barrier cannot deadlock.
    {
        const unsigned short* a0 = WhhT;
        const float* a1 = bh;
        const float* a2 = Wxh;
        const int*   a3 = X;
        const float* a4 = H0;
        unsigned short* a5 = Hst;
        float* a6 = Hfin;
        unsigned* a7 = bar;
        void* args[] = { &a0, &a1, &a2, &a3, &a4, &a5, &a6, &a7 };
        hipLaunchCooperativeKernel((void*)k_rnn_persist, dim3(NWG), dim3(256),
                                   args, 0, stream);
    }

    k_gemm_logits<<<dim3(LROWS/128, VOC/128), 256, 0, stream>>>(Hst + HN, BtHq, bq, out);
}